// Round 2
// baseline (274.277 us; speedup 1.0000x reference)
//
#include <hip/hip_runtime.h>
#include <math.h>

#define EPSF 1e-7f

// Exact replication of the reference _np_J entry (float64 math):
// J^l = diag((-1)^i) @ d^l(pi/2). At beta=pi/2, c=s=1/sqrt(2), so
// c^(2l+mp-m-2k) * s^(m-mp+2k) == 2^{-l} for every k.
__device__ __forceinline__ float j_entry(int ell, int mi, int mpi) {
    if (ell == 0) return 1.0f;
    const double fact[8] = {1.0, 1.0, 2.0, 6.0, 24.0, 120.0, 720.0, 5040.0};
    int m  = ell - mi;
    int mp = ell - mpi;
    double pref  = sqrt(fact[ell + m] * fact[ell - m] * fact[ell + mp] * fact[ell - mp]);
    double scale = 1.0 / (double)(1 << ell);
    int k0 = max(0, m - mp);
    int k1 = min(ell + m, ell - mp);
    double val = 0.0;
    for (int k = k0; k <= k1; ++k) {
        double denom = fact[ell + m - k] * fact[ell - mp - k] * fact[k + mp - m] * fact[k];
        double t = pref / denom * scale;
        val += ((m - mp + k) & 1) ? -t : t;
    }
    return (float)((mi & 1) ? -val : val);
}

// One EDGE per WAVE per iteration. Lane l owns row r = l>>2, cols [4c, 4c+4),
// c = l&3, of the 16x16 output -> the single wave-wide float4 store covers the
// whole 1KB matrix with lane-contiguous addresses (perfect coalescing).
//
// Branch-free math via a fixed 7-slot m-frame (slot s <-> m = 3-s, zero-padded):
//   u(m) = cos(m_i a)*J[li, L-m] + sin(m_i a)*J[2L-li, L-m]
//   w(m) = u(m)*cos(m b) - u(-m)*sin(m b)          (u[6-s] is u(-m))
//   res[j] = sum_s w[s] * M[s][j],  M[s][j] = J[L-m_s, (4c+j) - L^2] (0 outside)
__global__ __launch_bounds__(256)
void EdgeRotation_49435073577214_kernel(const float* __restrict__ ev,
                                        float* __restrict__ out, int E) {
    const int gtid   = (int)(blockIdx.x * blockDim.x + threadIdx.x);
    const int lane   = (int)(threadIdx.x & 63);
    const int wave   = gtid >> 6;
    const int nwaves = (int)((gridDim.x * blockDim.x) >> 6);

    const int r = lane >> 2;       // output row 0..15
    const int c = lane & 3;        // col group: cols 4c..4c+3

    int L = (r == 0) ? 0 : (r < 4) ? 1 : (r < 9) ? 2 : 3;
    int li  = r - L * L;
    int m_i = L - li;
    int am  = (m_i < 0) ? -m_i : m_i;

    // ---- per-lane constant tables (init once; static indexing thereafter) ----
    float Jmu[7], Jrev[7], M[7][4];
#pragma unroll
    for (int s = 0; s < 7; ++s) {
        int ms  = 3 - s;
        int ams = (ms < 0) ? -ms : ms;
        bool in = (ams <= L);
        int  kp = L - ms;               // within-block row index for slot s
        Jmu[s]  = in ? j_entry(L, li, kp) : 0.0f;
        Jrev[s] = in ? j_entry(L, 2 * L - li, kp) : 0.0f;
#pragma unroll
        for (int j = 0; j < 4; ++j) {
            int col = 4 * c + j;
            int v   = col - L * L;
            M[s][j] = (in && v >= 0 && v <= 2 * L) ? j_entry(L, kp, v) : 0.0f;
        }
    }
    // alpha-angle selection masks (per-lane constants, arithmetic select)
    float sA0 = (am == 0) ? 1.0f : 0.0f;
    float sA1 = (am == 1) ? 1.0f : 0.0f;
    float sA2 = (am == 2) ? 1.0f : 0.0f;
    float sA3 = (am == 3) ? 1.0f : 0.0f;
    float sgn = (m_i < 0) ? -1.0f : 1.0f;
    float tA1 = sgn * sA1, tA2 = sgn * sA2, tA3 = sgn * sA3;

    for (int e = wave; e < E; e += nwaves) {
        float x = ev[3 * e + 0];     // wave-uniform -> HW broadcast
        float y = ev[3 * e + 1];
        float z = ev[3 * e + 2];

        float r2xy = x * x + y * y;
        float rr   = sqrtf(r2xy + z * z);
        float cb   = z / fmaxf(rr, EPSF);
        cb = fminf(fmaxf(cb, -1.0f + EPSF), 1.0f - EPSF);
        float sb = sqrtf(fmaxf(1.0f - cb * cb, 0.0f));   // beta in [0,pi]

        bool  degen   = (fabsf(x) < EPSF) && (fabsf(y) < EPSF);
        float inv_rho = 1.0f / fmaxf(sqrtf(r2xy), EPSF);
        float ca1 = degen ? 1.0f : x * inv_rho;
        float sa1 = degen ? 0.0f : y * inv_rho;

        // multi-angles (Chebyshev)
        float CA2 = ca1 * ca1 - sa1 * sa1,  SA2 = 2.0f * ca1 * sa1;
        float CA3 = CA2 * ca1 - SA2 * sa1,  SA3 = SA2 * ca1 + CA2 * sa1;
        float CB2 = cb * cb - sb * sb,      SB2 = 2.0f * cb * sb;
        float CB3 = CB2 * cb - SB2 * sb,    SB3 = SB2 * cb + CB2 * sb;

        // per-lane cos/sin(m_i * alpha) via arithmetic select (no dyn index)
        float ca = sA0 + sA1 * ca1 + sA2 * CA2 + sA3 * CA3;
        float sa = tA1 * sa1 + tA2 * SA2 + tA3 * SA3;

        // per-slot cos/sin(m_s * beta), m_s = 3-s  (all static)
        float cosb[7] = { CB3, CB2, cb, 1.0f, cb, CB2, CB3 };
        float sinb[7] = { SB3, SB2, sb, 0.0f, -sb, -SB2, -SB3 };

        float u[7];
#pragma unroll
        for (int s = 0; s < 7; ++s)
            u[s] = ca * Jmu[s] + sa * Jrev[s];

        float w[7];
#pragma unroll
        for (int s = 0; s < 7; ++s)
            w[s] = fmaf(-u[6 - s], sinb[s], u[s] * cosb[s]);

        float4 o;
        {
            float a0 = 0.f, a1 = 0.f, a2 = 0.f, a3 = 0.f;
#pragma unroll
            for (int s = 0; s < 7; ++s) {
                a0 = fmaf(w[s], M[s][0], a0);
                a1 = fmaf(w[s], M[s][1], a1);
                a2 = fmaf(w[s], M[s][2], a2);
                a3 = fmaf(w[s], M[s][3], a3);
            }
            o = make_float4(a0, a1, a2, a3);
        }

        // wave-wide dense 1KB store: lane l -> floats [4l, 4l+4) of this edge
        reinterpret_cast<float4*>(out + (size_t)e * 256)[lane] = o;
    }
}

extern "C" void kernel_launch(void* const* d_in, const int* in_sizes, int n_in,
                              void* d_out, int out_size, void* d_ws, size_t ws_size,
                              hipStream_t stream) {
    const float* ev  = (const float*)d_in[0];
    float*       out = (float*)d_out;
    int E = in_sizes[0] / 3;   // [E,3] flat

    dim3 grid(2048), block(256);
    hipLaunchKernelGGL(EdgeRotation_49435073577214_kernel, grid, block, 0, stream,
                       ev, out, E);
}

// Round 3
// 101.500 us; speedup vs baseline: 2.7022x; 2.7022x over previous
//
#include <hip/hip_runtime.h>
#include <math.h>

// ---------------- compile-time J tables (reference _np_J, float64) ----------
// J^l = diag((-1)^i) @ d^l(pi/2). At beta=pi/2, c=s=1/sqrt(2):
// c^(2l+mp-m-2k) * s^(m-mp+2k) == 2^{-l} for every k.
constexpr double csqrt(double a) {
    double x = a > 1.0 ? a : 1.0;
    for (int i = 0; i < 48; ++i) x = 0.5 * (x + a / x);
    return x;
}

constexpr double j_entry_d(int ell, int mi, int mpi) {
    if (ell == 0) return 1.0;
    double fact[8] = {1.0, 1.0, 2.0, 6.0, 24.0, 120.0, 720.0, 5040.0};
    int m  = ell - mi;
    int mp = ell - mpi;
    double pref  = csqrt(fact[ell + m] * fact[ell - m] * fact[ell + mp] * fact[ell - mp]);
    double scale = 1.0 / (double)(1 << ell);
    int k0 = (m - mp) > 0 ? (m - mp) : 0;
    int k1 = (ell + m) < (ell - mp) ? (ell + m) : (ell - mp);
    double val = 0.0;
    for (int k = k0; k <= k1; ++k) {
        double denom = fact[ell + m - k] * fact[ell - mp - k] * fact[k + mp - m] * fact[k];
        double t = pref / denom * scale;
        val += ((m - mp + k) & 1) ? -t : t;
    }
    return (mi & 1) ? -val : val;
}

// Per-lane packed constants. Lane l: row r = l>>2, col group c = l&3.
// [0..6]   jmu[s]  = J_L[li,   L-m_s]           (m_s = 3-s; 0 outside block)
// [7..13]  jrev[s] = J_L[2L-li, L-m_s]
// [14..41] M[s][j] = J_L[L-m_s, 4c+j - L^2]     (0 outside block)
// [42]     |m_i| as float   [43] sign(m_i)
struct alignas(16) Tabs { float t[64][48]; };

constexpr Tabs make_tabs() {
    Tabs T{};
    for (int lane = 0; lane < 64; ++lane) {
        int r = lane >> 2, c = lane & 3;
        int L  = (r == 0) ? 0 : (r < 4) ? 1 : (r < 9) ? 2 : 3;
        int li = r - L * L;
        int m_i = L - li;
        int am  = m_i < 0 ? -m_i : m_i;
        for (int s = 0; s < 7; ++s) {
            int ms  = 3 - s;
            int ams = ms < 0 ? -ms : ms;
            bool in = (ams <= L);
            int  kp = L - ms;
            T.t[lane][s]     = in ? (float)j_entry_d(L, li, kp) : 0.0f;
            T.t[lane][7 + s] = in ? (float)j_entry_d(L, 2 * L - li, kp) : 0.0f;
            for (int j = 0; j < 4; ++j) {
                int v = 4 * c + j - L * L;
                T.t[lane][14 + 4 * s + j] =
                    (in && v >= 0 && v <= 2 * L) ? (float)j_entry_d(L, kp, v) : 0.0f;
            }
        }
        T.t[lane][42] = (float)am;
        T.t[lane][43] = (m_i < 0) ? -1.0f : 1.0f;
        T.t[lane][44] = 0.0f; T.t[lane][45] = 0.0f;
        T.t[lane][46] = 0.0f; T.t[lane][47] = 0.0f;
    }
    return T;
}

__device__ constexpr Tabs g_tabs = make_tabs();

// One edge per wave per iteration; lane l stores floats [4l,4l+4) of the
// edge's 16x16 matrix -> one dense 1KB wave store. All heavy math in approx
// fp32 intrinsics; J constants from compile-time table.
__global__ __launch_bounds__(256)
void EdgeRotation_49435073577214_kernel(const float* __restrict__ ev,
                                        float* __restrict__ out,
                                        int E, int nwaves) {
    const int lane = (int)(threadIdx.x & 63);
    int wv = (int)(blockIdx.x * (blockDim.x >> 6) + (threadIdx.x >> 6));
    wv = __builtin_amdgcn_readfirstlane(wv);          // force SGPR -> s_loads

    const float* tp = g_tabs.t[lane];
    float jmu[7], jrev[7], M[7][4];
#pragma unroll
    for (int s = 0; s < 7; ++s) { jmu[s] = tp[s]; jrev[s] = tp[7 + s]; }
#pragma unroll
    for (int s = 0; s < 7; ++s)
#pragma unroll
        for (int j = 0; j < 4; ++j) M[s][j] = tp[14 + 4 * s + j];
    const float amf = tp[42], sgn = tp[43];

    int e  = wv;
    int ep = e < E ? e : 0;
    float x = ev[3 * ep], y = ev[3 * ep + 1], z = ev[3 * ep + 2];

    while (e < E) {
        const int en  = e + nwaves;
        const int epn = en < E ? en : 0;              // clamped prefetch
        const float xn = ev[3 * epn], yn = ev[3 * epn + 1], zn = ev[3 * epn + 2];

        const float r2   = fmaf(x, x, fmaf(y, y, z * z));
        const float rho2 = fmaf(x, x, y * y);
        const float rinv = __builtin_amdgcn_rsqf(fmaxf(r2, 1e-30f));
        float cb = z * rinv;
        cb = fminf(fmaxf(cb, -1.0f + 1e-7f), 1.0f - 1e-7f);
        const float sb = __builtin_amdgcn_sqrtf(fmaxf(fmaf(-cb, cb, 1.0f), 0.0f));

        const float rhoinv = __builtin_amdgcn_rsqf(fmaxf(rho2, 1e-30f));
        const bool  nd  = rho2 >= 1e-14f;             // non-degenerate
        const float ca1 = nd ? x * rhoinv : 1.0f;
        const float sa1 = nd ? y * rhoinv : 0.0f;

        // multi-angles (Chebyshev)
        const float CA2 = fmaf(ca1, ca1, -(sa1 * sa1));
        const float SA2 = 2.0f * ca1 * sa1;
        const float CA3 = fmaf(CA2, ca1, -(SA2 * sa1));
        const float SA3 = fmaf(SA2, ca1, CA2 * sa1);
        const float CB2 = fmaf(cb, cb, -(sb * sb));
        const float SB2 = 2.0f * cb * sb;
        const float CB3 = fmaf(CB2, cb, -(SB2 * sb));
        const float SB3 = fmaf(SB2, cb, CB2 * sb);

        // cos/sin(m_i * alpha), per-lane static select
        float ca = amf == 0.0f ? 1.0f : amf == 1.0f ? ca1 : amf == 2.0f ? CA2 : CA3;
        float sa = amf == 0.0f ? 0.0f : amf == 1.0f ? sa1 : amf == 2.0f ? SA2 : SA3;
        sa *= sgn;

        float u[7];
#pragma unroll
        for (int s = 0; s < 7; ++s) u[s] = fmaf(ca, jmu[s], sa * jrev[s]);

        float w[7];
        w[0] = fmaf(-u[6], SB3, u[0] * CB3);
        w[1] = fmaf(-u[5], SB2, u[1] * CB2);
        w[2] = fmaf(-u[4], sb , u[2] * cb );
        w[3] = u[3];
        w[4] = fmaf( u[2], sb , u[4] * cb );
        w[5] = fmaf( u[1], SB2, u[5] * CB2);
        w[6] = fmaf( u[0], SB3, u[6] * CB3);

        float a0 = 0.f, a1 = 0.f, a2 = 0.f, a3 = 0.f;
#pragma unroll
        for (int s = 0; s < 7; ++s) {
            a0 = fmaf(w[s], M[s][0], a0);
            a1 = fmaf(w[s], M[s][1], a1);
            a2 = fmaf(w[s], M[s][2], a2);
            a3 = fmaf(w[s], M[s][3], a3);
        }

        reinterpret_cast<float4*>(out + ((size_t)e << 8))[lane] =
            make_float4(a0, a1, a2, a3);

        x = xn; y = yn; z = zn; e = en;
    }
}

extern "C" void kernel_launch(void* const* d_in, const int* in_sizes, int n_in,
                              void* d_out, int out_size, void* d_ws, size_t ws_size,
                              hipStream_t stream) {
    const float* ev  = (const float*)d_in[0];
    float*       out = (float*)d_out;
    int E = in_sizes[0] / 3;   // [E,3] flat

    dim3 grid(2048), block(256);
    int nwaves = (int)((2048 * 256) / 64);
    hipLaunchKernelGGL(EdgeRotation_49435073577214_kernel, grid, block, 0, stream,
                       ev, out, E, nwaves);
}